// Round 8
// baseline (1901.708 us; speedup 1.0000x reference)
//
#include <hip/hip_runtime.h>
#include <hip/hip_bf16.h>
#include <math.h>

// ---------------- constants ----------------
// B=8 S=256 D=512 H=8 hd=64 DI=1024 DS=16 DC=4 DTR=32 DF=1024
// rows = B*S = 2048, MF = 2048*512 = 1048576 elements per stream plane

using bf16x8 = __attribute__((ext_vector_type(8))) short;
using floatx16 = __attribute__((ext_vector_type(16))) float;

__device__ inline short f2bf(float x) {
  __hip_bfloat16 h = __float2bfloat16(x);
  return *reinterpret_cast<short*>(&h);
}

// ---------------- reduction helpers (blockDim == 256) ----------------
__device__ inline float wave_sum(float v) {
#pragma unroll
  for (int o = 32; o > 0; o >>= 1) v += __shfl_xor(v, o, 64);
  return v;
}
__device__ inline float wave_maxf(float v) {
#pragma unroll
  for (int o = 32; o > 0; o >>= 1) v = fmaxf(v, __shfl_xor(v, o, 64));
  return v;
}
__device__ inline float block_sum(float v, float* sm) {
  v = wave_sum(v);
  if ((threadIdx.x & 63) == 0) sm[threadIdx.x >> 6] = v;
  __syncthreads();
  float r = sm[0] + sm[1] + sm[2] + sm[3];
  __syncthreads();
  return r;
}
__device__ inline float block_max(float v, float* sm) {
  v = wave_maxf(v);
  if ((threadIdx.x & 63) == 0) sm[threadIdx.x >> 6] = v;
  __syncthreads();
  float r = fmaxf(fmaxf(sm[0], sm[1]), fmaxf(sm[2], sm[3]));
  __syncthreads();
  return r;
}

// ---------------- f32 -> bf16 elementwise (n multiple of 1024) ----------------
__global__ __launch_bounds__(256) void cvt_bf16(const float* __restrict__ in,
                                                short* __restrict__ out) {
  int i = (blockIdx.x * 256 + threadIdx.x) * 4;
  float4 v = *(const float4*)(in + i);
  short4 o;
  o.x = f2bf(v.x); o.y = f2bf(v.y); o.z = f2bf(v.z); o.w = f2bf(v.w);
  *(short4*)(out + i) = o;
}

// ---------------- epilogue index helper ----------------
__device__ inline long long out_idx(int omode, int osec, int m, int n, int ldc,
                                    int zb) {
  if (omode == 0) return (long long)m * ldc + n;
  if (omode == 1)
    return (long long)(m >> 8) * 131072 + (long long)(n >> 6) * 16384 +
           (m & 255) * 64 + (n & 63);
  if (omode == 2)
    return (long long)(zb >> 3) * 131072 + (zb & 7) * 64 +
           (long long)m * 512 + n;
  const int sec = (n >> 9) + osec;
  const int d = n & 511;
  if (sec < 2)
    return (long long)sec * 1048576 +
           (((long long)(m >> 8) * 8 + (d >> 6)) * 256 + (m & 255)) * 64 +
           (d & 63);
  return 2LL * 1048576 + (long long)m * 512 + d;
}

// ---------------- 128x128 MFMA GEMM (m97 structure) --------------------------
// A: M x K bf16 (lda), W: N x K bf16 (ldw). Stream-batched only (z = stream).
// BK=32; per slab: global_load_lds width-16 staging (lane order == fragment
// layout), 32 MFMAs/block per barrier. 4 waves = 2x2 quadrants of 64x64;
// each wave 2x2 mfma_32x32x16 tiles.
__global__ __launch_bounds__(256) void gemm128(
    const short* __restrict__ A, int lda, long long sAo,
    const short* __restrict__ W, int ldw, long long sWo,
    const float* __restrict__ bias, long long sBias,
    const float* __restrict__ res, long long sRes,
    float* __restrict__ C, short* __restrict__ Cbf, int ldc, long long sCo,
    int K, int act, int omode, int osec) {
  __shared__ __align__(16) short Asl[4096];   // [kg8][row][8]
  __shared__ __align__(16) short Bsl[4096];
  const int zs = blockIdx.z;
  A += sAo * zs; W += sWo * zs;
  if (C) C += sCo * zs;
  if (Cbf) Cbf += sCo * zs;
  const int m0 = blockIdx.y * 128, n0 = blockIdx.x * 128;
  const int tid = threadIdx.x, lane = tid & 63, wv = tid >> 6;
  const int mq = (wv & 1) * 64, nq = (wv >> 1) * 64;
  const int r31 = lane & 31, half = lane >> 5;
  floatx16 acc[2][2] = {};
  // staging element indices: e = r*256 + tid; kg8 = e>>7, row = e&127
  const int e0 = tid, e1 = 256 + tid;
  const short* pa0 = A + (long long)(m0 + (e0 & 127)) * lda + (e0 >> 7) * 8;
  const short* pa1 = A + (long long)(m0 + (e1 & 127)) * lda + (e1 >> 7) * 8;
  const short* pb0 = W + (long long)(n0 + (e0 & 127)) * ldw + (e0 >> 7) * 8;
  const short* pb1 = W + (long long)(n0 + (e1 & 127)) * ldw + (e1 >> 7) * 8;
  short* la0 = Asl + e0 * 8;
  short* la1 = Asl + e1 * 8;
  short* lb0 = Bsl + e0 * 8;
  short* lb1 = Bsl + e1 * 8;
  // fragment read bases
  const short* raLo = Asl + (half * 128 + mq + r31) * 8;
  const short* raHi = Asl + ((2 + half) * 128 + mq + r31) * 8;
  const short* rbLo = Bsl + (half * 128 + nq + r31) * 8;
  const short* rbHi = Bsl + ((2 + half) * 128 + nq + r31) * 8;
  for (int k0 = 0; k0 < K; k0 += 32) {
    if (k0) __syncthreads();   // fragment reads of previous slab done
    __builtin_amdgcn_global_load_lds(
        (const __attribute__((address_space(1))) void*)(pa0 + k0),
        (__attribute__((address_space(3))) void*)la0, 16, 0, 0);
    __builtin_amdgcn_global_load_lds(
        (const __attribute__((address_space(1))) void*)(pa1 + k0),
        (__attribute__((address_space(3))) void*)la1, 16, 0, 0);
    __builtin_amdgcn_global_load_lds(
        (const __attribute__((address_space(1))) void*)(pb0 + k0),
        (__attribute__((address_space(3))) void*)lb0, 16, 0, 0);
    __builtin_amdgcn_global_load_lds(
        (const __attribute__((address_space(1))) void*)(pb1 + k0),
        (__attribute__((address_space(3))) void*)lb1, 16, 0, 0);
    __syncthreads();           // vmcnt drained by barrier semantics
    const bf16x8 a0L = *(const bf16x8*)raLo;
    const bf16x8 a0H = *(const bf16x8*)raHi;
    const bf16x8 a1L = *(const bf16x8*)(raLo + 32 * 8);
    const bf16x8 a1H = *(const bf16x8*)(raHi + 32 * 8);
    const bf16x8 b0L = *(const bf16x8*)rbLo;
    const bf16x8 b0H = *(const bf16x8*)rbHi;
    const bf16x8 b1L = *(const bf16x8*)(rbLo + 32 * 8);
    const bf16x8 b1H = *(const bf16x8*)(rbHi + 32 * 8);
    acc[0][0] = __builtin_amdgcn_mfma_f32_32x32x16_bf16(a0L, b0L, acc[0][0], 0, 0, 0);
    acc[0][0] = __builtin_amdgcn_mfma_f32_32x32x16_bf16(a0H, b0H, acc[0][0], 0, 0, 0);
    acc[0][1] = __builtin_amdgcn_mfma_f32_32x32x16_bf16(a0L, b1L, acc[0][1], 0, 0, 0);
    acc[0][1] = __builtin_amdgcn_mfma_f32_32x32x16_bf16(a0H, b1H, acc[0][1], 0, 0, 0);
    acc[1][0] = __builtin_amdgcn_mfma_f32_32x32x16_bf16(a1L, b0L, acc[1][0], 0, 0, 0);
    acc[1][0] = __builtin_amdgcn_mfma_f32_32x32x16_bf16(a1H, b0H, acc[1][0], 0, 0, 0);
    acc[1][1] = __builtin_amdgcn_mfma_f32_32x32x16_bf16(a1L, b1L, acc[1][1], 0, 0, 0);
    acc[1][1] = __builtin_amdgcn_mfma_f32_32x32x16_bf16(a1H, b1H, acc[1][1], 0, 0, 0);
  }
#pragma unroll
  for (int j = 0; j < 2; ++j) {
    const int n = n0 + nq + j * 32 + r31;
    const float bvb = bias ? bias[sBias * zs + n] : 0.f;
#pragma unroll
    for (int i = 0; i < 2; ++i) {
#pragma unroll
      for (int r = 0; r < 16; ++r) {
        const int m = m0 + mq + i * 32 + (r & 3) + 8 * (r >> 2) + 4 * half;
        float v = acc[i][j][r] + bvb;
        if (act == 1) v = fmaxf(v, 0.f) + log1pf(expf(-fabsf(v)));
        else if (act == 2) v = fmaxf(v, 0.f);
        if (res) v += res[sRes * zs + (long long)m * ldc + n];
        const long long idx = out_idx(omode, osec, m, n, ldc, 0);
        if (C) C[idx] = v;
        if (Cbf) Cbf[idx] = f2bf(v);
      }
    }
  }
}

// ---------------- bf16 MFMA GEMM 64-tile, generalized batch ------------------
__global__ __launch_bounds__(256) void gemm_bf16(
    const short* __restrict__ A, int lda, long long sA, long long sAo,
    const short* __restrict__ W, int ldw, long long sW, long long sWo,
    const float* __restrict__ bias, long long sBias,
    const float* __restrict__ res, long long sRes,
    float* __restrict__ C, short* __restrict__ Cbf, int ldc,
    long long sC, long long sCo,
    int K, float alpha, int act, int omode, int osec, int zdiv) {
  __shared__ short As[4 * 528];
  __shared__ short Bs[4 * 528];
  const int bz = blockIdx.z;
  const int zs = bz / zdiv, zb = bz % zdiv;
  A += sA * zb + sAo * zs;
  W += sW * zb + sWo * zs;
  if (C) C += sC * zb + sCo * zs;
  if (Cbf) Cbf += sC * zb + sCo * zs;
  const int m0 = blockIdx.y * 64, n0 = blockIdx.x * 64;
  const int tid = threadIdx.x, lane = tid & 63, wv = tid >> 6;
  const int mq = (wv & 1) * 32, nq = (wv >> 1) * 32;
  const int r31 = lane & 31, half = lane >> 5;
  const int mA = tid >> 2, kgA = tid & 3;
  floatx16 acc = {};
  const short* pa = A + (long long)(m0 + mA) * lda + kgA * 8;
  const short* pb = W + (long long)(n0 + mA) * ldw + kgA * 8;
  short* wa = As + kgA * 528 + mA * 8;
  short* wb = Bs + kgA * 528 + mA * 8;
  const short* ra = As + (mq + r31) * 8 + half * 528;
  const short* rb = Bs + (nq + r31) * 8 + half * 528;
  bf16x8 av = *(const bf16x8*)pa;
  bf16x8 bv = *(const bf16x8*)pb;
  for (int k0 = 0; k0 < K; k0 += 32) {
    __syncthreads();
    *(bf16x8*)wa = av;
    *(bf16x8*)wb = bv;
    __syncthreads();
    if (k0 + 32 < K) {
      av = *(const bf16x8*)(pa + k0 + 32);
      bv = *(const bf16x8*)(pb + k0 + 32);
    }
    acc = __builtin_amdgcn_mfma_f32_32x32x16_bf16(
        *(const bf16x8*)ra, *(const bf16x8*)rb, acc, 0, 0, 0);
    acc = __builtin_amdgcn_mfma_f32_32x32x16_bf16(
        *(const bf16x8*)(ra + 2 * 528), *(const bf16x8*)(rb + 2 * 528), acc, 0, 0, 0);
  }
  const int n = n0 + nq + r31;
  const float bvb = bias ? bias[sBias * zs + n] : 0.f;
#pragma unroll
  for (int r = 0; r < 16; ++r) {
    const int m = m0 + mq + (r & 3) + 8 * (r >> 2) + 4 * half;
    float v = acc[r] * alpha + bvb;
    if (act == 1) v = fmaxf(v, 0.f) + log1pf(expf(-fabsf(v)));
    else if (act == 2) v = fmaxf(v, 0.f);
    if (res) v += res[sRes * zs + (long long)m * ldc + n];
    const long long idx = out_idx(omode, osec, m, n, ldc, zb);
    if (C) C[idx] = v;
    if (Cbf) Cbf[idx] = f2bf(v);
  }
}

// ---------------- LayerNorm, stream-batched (2048 rows/stream) ----------------
__device__ inline float pe_val(int bi, int c) {
  float f = expf((float)(c & ~1) * (-9.210340371976184f / 512.f));
  float arg = (float)bi * f;
  return (c & 1) ? cosf(arg) : sinf(arg);
}
__global__ __launch_bounds__(256) void ln_kernel(
    const float* __restrict__ in1, long long s1,
    const float* __restrict__ in2, long long s2,
    const float* __restrict__ in3,
    const float* __restrict__ g, const float* __restrict__ bb, long long sg,
    float* __restrict__ out, short* __restrict__ obf, long long so,
    int mode, int add_pe) {
  __shared__ float sm[4];
  const int row = blockIdx.x, tid = threadIdx.x;
  const int stream = row >> 11, lr = row & 2047;
  in1 += stream * s1;
  if (in2) in2 += stream * s2;
  g += stream * sg; bb += stream * sg;
  const long long base = (long long)lr * 512;
  const long long obase = stream * so + base;
  float x0 = in1[base + tid];
  float x1 = in1[base + tid + 256];
  if (in2) { x0 += in2[base + tid]; x1 += in2[base + tid + 256]; }
  if (in3) { x0 += in3[base + tid]; x1 += in3[base + tid + 256]; }
  if (add_pe) {
    int bi = lr >> 8;
    x0 += pe_val(bi, tid);
    x1 += pe_val(bi, tid + 256);
  }
  float m = block_sum(x0 + x1, sm) * (1.f / 512.f);
  float d0 = x0 - m, d1 = x1 - m;
  float ss = block_sum(d0 * d0 + d1 * d1, sm);
  float r0, r1;
  if (mode == 0) {
    float rstd = rsqrtf(ss * (1.f / 512.f) + 1e-5f);
    r0 = d0 * rstd * g[tid] + bb[tid];
    r1 = d1 * rstd * g[tid + 256] + bb[tid + 256];
  } else {
    float s = sqrtf(ss * (1.f / 511.f));
    float inv = 1.f / (s + 1e-6f);
    r0 = g[tid] * d0 * inv + bb[tid];
    r1 = g[tid + 256] * d1 * inv + bb[tid + 256];
  }
  if (out) { out[obase + tid] = r0; out[obase + tid + 256] = r1; }
  if (obf) { obf[obase + tid] = f2bf(r0); obf[obase + tid + 256] = f2bf(r1); }
}

// ---------------- causal depthwise conv + SiLU, 3-layer batched ----------------
__global__ __launch_bounds__(256) void conv_silu(
    const float* __restrict__ xz, const float* __restrict__ cw,
    const float* __restrict__ cb, float* __restrict__ u2,
    short* __restrict__ u2bf) {
  int gid = blockIdx.x * 256 + threadIdx.x;
  int lay = gid >> 21;
  int idx = gid & 2097151;
  int c = idx & 1023, t = (idx >> 10) & 255, b = idx >> 18;
  const float* base = xz + (long long)lay * 4194304 + (long long)b * 256 * 2048;
  cw += lay * 4096; cb += lay * 1024;
  float acc = cb[c];
#pragma unroll
  for (int k = 0; k < 4; ++k) {
    int tt = t + k - 3;
    if (tt >= 0) acc += base[tt * 2048 + c] * cw[c * 4 + k];
  }
  float v = acc / (1.f + expf(-acc));
  u2[gid] = v;
  u2bf[gid] = f2bf(v);
}

// ---------------- selective-scan, single-buffer LDS + reg prefetch ----------
__global__ __launch_bounds__(256) void scan_kernel(
    const float* __restrict__ delta, const float* __restrict__ u2,
    const float* __restrict__ xz, const float* __restrict__ xdbl,
    const float* __restrict__ Alog, const float* __restrict__ Dp,
    short* __restrict__ ys) {
  __shared__ float sdel[64][16];
  __shared__ float su[64][16];
  __shared__ float sz[64][16];
  __shared__ float sxd[64][32];
  __shared__ float sy[64][16];
  const int lay = blockIdx.y >> 3, b = blockIdx.y & 7;
  delta += (long long)lay * 2097152;
  u2 += (long long)lay * 2097152;
  xz += (long long)lay * 4194304;
  xdbl += (long long)lay * 131072;
  Alog += lay * 16384;
  Dp += lay * 1024;
  ys += (long long)lay * 2097152;
  const int tid = threadIdx.x;
  const int lane = tid & 63;
  const int wv = tid >> 6;
  const int s = lane >> 2;
  const int dsub = lane & 3;
  const int dl = wv * 4 + dsub;
  const int d0 = blockIdx.x * 16;
  const int d = d0 + dl;
  const float A = -expf(Alog[d * 16 + s]);
  const float Dd = Dp[d];
  const long long rowbase = (long long)b * 256;
  float rdel[4], ru[4], rz[4], rxd[8];
  auto issue = [&](int c) {
    const int t0 = c * 64;
#pragma unroll
    for (int k = 0; k < 4; ++k) {
      int e = k * 256 + tid;
      int t = e >> 4, dd = e & 15;
      long long r = rowbase + t0 + t;
      rdel[k] = delta[r * 1024 + d0 + dd];
      ru[k]   = u2[r * 1024 + d0 + dd];
      rz[k]   = xz[r * 2048 + 1024 + d0 + dd];
    }
#pragma unroll
    for (int k = 0; k < 8; ++k) {
      int e = k * 256 + tid;
      int t = e >> 5, j = e & 31;
      rxd[k] = xdbl[(rowbase + t0 + t) * 64 + 32 + j];
    }
  };
  auto commit = [&]() {
#pragma unroll
    for (int k = 0; k < 4; ++k) {
      int e = k * 256 + tid;
      int t = e >> 4, dd = e & 15;
      sdel[t][dd] = rdel[k]; su[t][dd] = ru[k]; sz[t][dd] = rz[k];
    }
#pragma unroll
    for (int k = 0; k < 8; ++k) {
      int e = k * 256 + tid;
      int t = e >> 5, j = e & 31;
      sxd[t][j] = rxd[k];
    }
  };
  issue(0);
  commit();
  float h = 0.f;
  for (int c = 0; c < 4; ++c) {
    __syncthreads();
    if (c < 3) issue(c + 1);
#pragma unroll 4
    for (int t = 0; t < 64; ++t) {
      const float dt = sdel[t][dl];
      const float uu = su[t][dl];
      const float Bs = sxd[t][s];
      const float Cs = sxd[t][16 + s];
      h = __expf(dt * A) * h + dt * uu * Bs;
      float pp = h * Cs;
      pp += __shfl_xor(pp, 4, 64);
      pp += __shfl_xor(pp, 8, 64);
      pp += __shfl_xor(pp, 16, 64);
      pp += __shfl_xor(pp, 32, 64);
      if (s == 0) {
        const float zz = sz[t][dl];
        sy[t][dl] = (pp + Dd * uu) * (zz / (1.f + expf(-zz)));
      }
    }
    __syncthreads();
    const int t0 = c * 64;
#pragma unroll
    for (int k = 0; k < 4; ++k) {
      int e = k * 256 + tid;
      int t = e >> 4, dd = e & 15;
      ys[(rowbase + t0 + t) * 1024 + d0 + dd] = f2bf(sy[t][dd]);
    }
    if (c < 3) commit();
  }
}

// ---------------- softmax rows of 256: f32 in -> bf16 out ----------------
__global__ __launch_bounds__(256) void softmax_rows(const float* __restrict__ S,
                                                    short* __restrict__ Sbf) {
  __shared__ float sm[4];
  const float* p = S + (long long)blockIdx.x * 256;
  float v = p[threadIdx.x];
  float m = block_max(v, sm);
  float e = expf(v - m);
  float s = block_sum(e, sm);
  Sbf[(long long)blockIdx.x * 256 + threadIdx.x] = f2bf(e / s);
}

// ---------------- V transpose (bf16, 3 streams): -> (B,H,hd,S) ----------------
__global__ __launch_bounds__(256) void to_heads_t(const short* __restrict__ in,
                                                  short* __restrict__ out) {
  int e = blockIdx.x * 256 + threadIdx.x;
  int stream = e >> 20;
  int inner = e & 1048575;
  int s = inner & 255, c = (inner >> 8) & 63, h = (inner >> 14) & 7, b = inner >> 17;
  out[(long long)stream * 1048576 + inner] =
      in[(long long)stream * 3145728 + 2097152 + ((b * 256 + s) * 512) + h * 64 + c];
}

// ---------------- host orchestration ----------------
extern "C" void kernel_launch(void* const* d_in, const int* in_sizes, int n_in,
                              void* d_out, int out_size, void* d_ws, size_t ws_size,
                              hipStream_t stream) {
  (void)in_sizes; (void)n_in; (void)out_size; (void)ws_size;
  const float* text   = (const float*)d_in[0];
  const float* video  = (const float*)d_in[1];
  const float* audio  = (const float*)d_in[2];
  const float* emb_w  = (const float*)d_in[3];
  const float* emb_b  = (const float*)d_in[4];
  const float* ada_a  = (const float*)d_in[5];
  const float* ada_b  = (const float*)d_in[6];
  const float* m_in_w = (const float*)d_in[7];
  const float* m_cw   = (const float*)d_in[8];
  const float* m_cb   = (const float*)d_in[9];
  const float* m_xp   = (const float*)d_in[10];
  const float* m_dtw  = (const float*)d_in[11];
  const float* m_dtb  = (const float*)d_in[12];
  const float* m_Alog = (const float*)d_in[13];
  const float* m_Dp   = (const float*)d_in[14];
  const float* m_ow   = (const float*)d_in[15];
  const float* m_lng  = (const float*)d_in[16];
  const float* m_lnb  = (const float*)d_in[17];
  const float* qkv_w  = (const float*)d_in[18];
  const float* qkv_b  = (const float*)d_in[19];
  const float* aout_w = (const float*)d_in[20];
  const float* aout_b = (const float*)d_in[21];
  const float* sln_g  = (const float*)d_in[22];
  const float* sln_b  = (const float*)d_in[23];
  const float* f_w1   = (const float*)d_in[24];
  const float* f_b1   = (const float*)d_in[25];
  const float* f_w2   = (const float*)d_in[26];
  const float* f_b2   = (const float*)d_in[27];
  const float* f_lng  = (const float*)d_in[28];
  const float* f_lnb  = (const float*)d_in[29];
  const float* n1_g   = (const float*)d_in[30];
  const float* n1_b   = (const float*)d_in[31];
  float* outp = (float*)d_out;

  const long long MF = 1048576;   // 2048*512

  // ---------- workspace arenas ----------
  float* ws = (float*)d_ws;
  size_t off = 0;
  auto alloc = [&](size_t n) { float* p = ws + off; off += n; return p; };
  auto allocs = [&](size_t n_bf16) { return (short*)alloc((n_bf16 + 1) / 2); };
  float* sb0    = alloc(6 * MF);
  short* sbbf0  = allocs(6 * MF);
  short* inbf   = allocs(3 * MF);
  float* xzA    = alloc(3 * 4194304);       // xz | scoresF
  float* u2A    = alloc(3 * 2097152);       // u2 f32 | scoresBf
  float* dlA    = alloc(3 * 2097152);       // dl f32 | qkvA (9M shorts)
  short* ysA    = allocs(3 * 2097152);      // ys bf16 | vtA+obA
  float* xdblA  = alloc(3 * 131072);
  short* xdblbfA= allocs(3 * 131072);
  float* mtmpA  = alloc(3 * MF);            // mtmp | h2
  short* u2bfA  = allocs(3 * 2097152);      // u2bf | hbufbf
  short* n1bfA  = allocs(3 * MF);
  short* n2bfA  = allocs(3 * MF);
  short* embbf   = allocs(512 * 512);
  short* minbf   = allocs(6 * 1048576);
  short* mxpbf   = allocs(6 * 65536);
  short* mdtwbf  = allocs(6 * 32768);
  short* mowbf   = allocs(6 * 524288);
  short* qkvwbf  = allocs(9 * 786432);
  short* aoutwbf = allocs(9 * 262144);
  short* fw1bf   = allocs(3 * 524288);
  short* fw2bf   = allocs(3 * 524288);

  float* scoresF  = xzA;
  short* scoresBf = (short*)u2A;
  short* qkvA     = (short*)dlA;
  short* vtA      = ysA;
  short* obA      = ysA + 3145728;
  short* hbufbfA  = u2bfA;
  float* h2A      = mtmpA;

  auto cvt = [&](const float* in, short* out, int n) {
    cvt_bf16<<<n / 1024, 256, 0, stream>>>(in, out);
  };
  auto gemm = [&](const short* A, int lda, long long sA, long long sAo,
                  const short* W, int ldw, long long sW, long long sWo,
                  const float* bias, long long sB,
                  const float* res, long long sR,
                  float* C, short* Cbf, int ldc, long long sC, long long sCo,
                  int M, int N, int K, float alpha, int act,
                  int omode, int osec, int zdiv, int batch) {
    dim3 g(N / 64, M / 64, batch);
    gemm_bf16<<<g, 256, 0, stream>>>(A, lda, sA, sAo, W, ldw, sW, sWo,
                                     bias, sB, res, sR, C, Cbf, ldc, sC, sCo,
                                     K, alpha, act, omode, osec, zdiv);
  };
  auto g128 = [&](const short* A, int lda, long long sAo,
                  const short* W, int ldw, long long sWo,
                  const float* bias, long long sB,
                  const float* res, long long sR,
                  float* C, short* Cbf, int ldc, long long sCo,
                  int M, int N, int K, int act, int omode, int osec) {
    dim3 g(N / 128, M / 128, 3);
    gemm128<<<g, 256, 0, stream>>>(A, lda, sAo, W, ldw, sWo, bias, sB,
                                   res, sR, C, Cbf, ldc, sCo, K, act,
                                   omode, osec);
  };
  auto ln = [&](const float* i1, long long s1, const float* i2, long long s2,
                const float* i3, const float* g, const float* b, long long sg,
                float* o, short* obf, long long so, int mode, int pe,
                int nblocks) {
    ln_kernel<<<nblocks, 256, 0, stream>>>(i1, s1, i2, s2, i3, g, b, sg,
                                           o, obf, so, mode, pe);
  };

  // ---- pre-convert all weights to bf16 ----
  cvt(emb_w,  embbf,   512 * 512);
  cvt(m_in_w, minbf,   6 * 1048576);
  cvt(m_xp,   mxpbf,   6 * 65536);
  cvt(m_dtw,  mdtwbf,  6 * 32768);
  cvt(m_ow,   mowbf,   6 * 524288);
  cvt(qkv_w,  qkvwbf,  9 * 786432);
  cvt(aout_w, aoutwbf, 9 * 262144);
  cvt(f_w1,   fw1bf,   3 * 524288);
  cvt(f_w2,   fw2bf,   3 * 524288);

  // ---- mamba group (layers g0..g0+2 on sb[0..2]) ----
  auto mamba3 = [&](int g0) {
    g128(sbbf0, 512, MF,  minbf + (size_t)g0 * 1048576, 512, 1048576,
         nullptr, 0, nullptr, 0,  xzA, nullptr, 2048, 4194304,
         2048, 2048, 512, 0, 0, 0);
    conv_silu<<<24576, 256, 0, stream>>>(xzA, m_cw + (size_t)g0 * 4096,
                                         m_cb + (size_t)g0 * 1024, u2A, u2bfA);
    gemm(u2bfA, 1024, 0, 2097152,  mxpbf + (size_t)g0 * 65536, 1024, 0, 65536,
         nullptr, 0, nullptr, 0,  xdblA, xdblbfA, 64, 0, 131072,
         2048, 64, 1024, 1.f, 0, 0, 0, 1, 3);
    gemm(xdblbfA, 64, 0, 131072,  mdtwbf + (size_t)g0 * 32768, 32, 0, 32768,
         m_dtb + (size_t)g0 * 1024, 1024, nullptr, 0,
         dlA, nullptr, 1024, 0, 2097152,
         2048, 1024, 32, 1.f, 1, 0, 0, 1, 3);
    scan_kernel<<<dim3(64, 24), 256, 0, stream>>>(
        dlA, u2A, xzA, xdblA, m_Alog + (size_t)g0 * 16384,
        m_Dp + (size_t)g0 * 1024, ysA);
    g128(ysA, 1024, 2097152,  mowbf + (size_t)g0 * 524288, 1024, 524288,
         nullptr, 0, nullptr, 0,  mtmpA, nullptr, 512, MF,
         2048, 512, 1024, 0, 0, 0);
    ln(sb0, MF, mtmpA, MF, nullptr, m_lng + (size_t)g0 * 512,
       m_lnb + (size_t)g0 * 512, 512, sb0, sbbf0, MF, 0, 0, 6144);
  };

  // ---- attention core (after q/k/v in qkvA) ----
  auto attn_core = [&](int i0, const float* s1b, float* outb, short* outbfb) {
    to_heads_t<<<12288, 256, 0, stream>>>(qkvA, vtA);
    gemm(qkvA, 64, 16384, 3 * MF,  qkvA + MF, 64, 16384, 3 * MF,
         nullptr, 0, nullptr, 0,  scoresF, nullptr, 256, 65536, 4194304,
         256, 256, 64, 0.125f, 0, 0, 0, 64, 192);
    softmax_rows<<<49152, 256, 0, stream>>>(scoresF, scoresBf);
    gemm(scoresBf, 256, 65536, 4194304,  vtA, 256, 16384, MF,
         nullptr, 0, nullptr, 0,  nullptr, obA, 512, 0, MF,
         256, 64, 256, 1.f, 0, 2, 0, 64, 192);
    g128(obA, 512, MF,  aoutwbf + (size_t)i0 * 262144, 512, 262144,
         aout_b + (size_t)i0 * 512, 512,  s1b, MF,
         outb, outbfb, 512, MF, 2048, 512, 512, 0, 0, 0);
  };

  auto attn_self = [&](int i0, const float* s1b, float* outb, short* outbfb) {
    ln(s1b, MF, nullptr, 0, nullptr, sln_g + (size_t)i0 * 512,
       sln_b + (size_t)i0 * 512, 512, nullptr, n1bfA, MF, 0, 0, 6144);
    g128(n1bfA, 512, MF,  qkvwbf + (size_t)i0 * 786432, 512, 786432,
         qkv_b + (size_t)i0 * 1536, 1536, nullptr, 0,
         nullptr, qkvA, 0, 3 * MF, 2048, 1536, 512, 0, 3, 0);
    attn_core(i0, s1b, outb, outbfb);
  };

  auto attn_cross = [&](int i0, const float* s1b, const float* s2p0,
                        const float* s2p1, const float* s2p2,
                        float* outb, short* outbfb) {
    ln(s1b, MF, nullptr, 0, nullptr, sln_g + (size_t)i0 * 512,
       sln_b + (size_t)i0 * 512, 512, nullptr, n1bfA, MF, 0, 0, 6144);
    const float* s2p[3] = {s2p0, s2p1, s2p2};
    for (int s = 0; s < 3; ++s)
      ln(s2p[s], 0, nullptr, 0, nullptr, sln_g + (size_t)(i0 + s) * 512,
         sln_b + (size_t)(i0 + s) * 512, 0, nullptr, n2bfA + s * MF, 0,
         0, 0, 2048);
    g128(n1bfA, 512, MF,  qkvwbf + (size_t)i0 * 786432, 512, 786432,
         qkv_b + (size_t)i0 * 1536, 1536, nullptr, 0,
         nullptr, qkvA, 0, 3 * MF, 2048, 512, 512, 0, 1, 0);
    g128(n2bfA, 512, MF,  qkvwbf + (size_t)i0 * 786432 + 262144, 512, 786432,
         qkv_b + (size_t)i0 * 1536 + 512, 1536, nullptr, 0,
         nullptr, qkvA, 0, 3 * MF, 2048, 1024, 512, 0, 3, 1);
    attn_core(i0, s1b, outb, outbfb);
  };

  // ---- stems ----
  const float* ins[3] = {text, video, audio};
  for (int j = 0; j < 3; ++j) cvt(ins[j], inbf + j * MF, MF);
  g128(inbf, 512, MF,  embbf, 512, 0,  emb_b, 0, nullptr, 0,
       sb0, nullptr, 512, MF, 2048, 512, 512, 0, 0, 0);
  ln(sb0, MF, nullptr, 0, nullptr, ada_a, ada_b, 0, sb0, sbbf0, MF, 1, 1, 6144);
  // ---- mamba 0..2 ----
  mamba3(0);
  // ---- self attention 0..2: sb[0..2] -> sb[3..5] ----
  attn_self(0, sb0, sb0 + 3 * MF, nullptr);
  // ---- cross attention 3..5 ----
  attn_cross(3, sb0 + 3 * MF, sb0 + 5 * MF, sb0 + 3 * MF, sb0 + 4 * MF,
             sb0, sbbf0);
  // ---- mamba 3..5 ----
  mamba3(3);
  // ---- self attention 6..8: sb[0..2] -> sb[3..5] ----
  attn_self(6, sb0, sb0 + 3 * MF, sbbf0 + 3 * MF);
  // ---- ffn 0..2 on sb[3..5] ----
  g128(sbbf0 + 3 * MF, 512, MF,  fw1bf, 512, 524288,
       f_b1, 1024, nullptr, 0,  nullptr, hbufbfA, 1024, 2097152,
       2048, 1024, 512, 2, 0, 0);
  g128(hbufbfA, 1024, 2097152,  fw2bf, 1024, 524288,
       f_b2, 512, nullptr, 0,  h2A, nullptr, 512, MF,
       2048, 512, 1024, 0, 0, 0);
  ln(sb0 + 3 * MF, MF, h2A, MF, nullptr, f_lng, f_lnb, 512,
     sb0 + 3 * MF, nullptr, MF, 1, 0, 6144);
  // ---- final norm: torch_ln(t+v+a) -> out ----
  ln(sb0 + 3 * MF, 0, sb0 + 4 * MF, 0, sb0 + 5 * MF, n1_g, n1_b, 0,
     outp, nullptr, 0, 0, 0, 2048);
}

// Round 9
// 1568.942 us; speedup vs baseline: 1.2121x; 1.2121x over previous
//
#include <hip/hip_runtime.h>
#include <hip/hip_bf16.h>
#include <math.h>

// ---------------- constants ----------------
// B=8 S=256 D=512 H=8 hd=64 DI=1024 DS=16 DC=4 DTR=32 DF=1024
// rows = B*S = 2048, MF = 2048*512 = 1048576 elements per stream plane

using bf16x8 = __attribute__((ext_vector_type(8))) short;
using floatx16 = __attribute__((ext_vector_type(16))) float;

__device__ inline short f2bf(float x) {
  __hip_bfloat16 h = __float2bfloat16(x);
  return *reinterpret_cast<short*>(&h);
}

// ---------------- reduction helpers (blockDim == 256) ----------------
__device__ inline float wave_sum(float v) {
#pragma unroll
  for (int o = 32; o > 0; o >>= 1) v += __shfl_xor(v, o, 64);
  return v;
}
__device__ inline float wave_maxf(float v) {
#pragma unroll
  for (int o = 32; o > 0; o >>= 1) v = fmaxf(v, __shfl_xor(v, o, 64));
  return v;
}
__device__ inline float block_sum(float v, float* sm) {
  v = wave_sum(v);
  if ((threadIdx.x & 63) == 0) sm[threadIdx.x >> 6] = v;
  __syncthreads();
  float r = sm[0] + sm[1] + sm[2] + sm[3];
  __syncthreads();
  return r;
}
__device__ inline float block_max(float v, float* sm) {
  v = wave_maxf(v);
  if ((threadIdx.x & 63) == 0) sm[threadIdx.x >> 6] = v;
  __syncthreads();
  float r = fmaxf(fmaxf(sm[0], sm[1]), fmaxf(sm[2], sm[3]));
  __syncthreads();
  return r;
}

// ---------------- f32 -> bf16 elementwise (n multiple of 1024) ----------------
__global__ __launch_bounds__(256) void cvt_bf16(const float* __restrict__ in,
                                                short* __restrict__ out) {
  int i = (blockIdx.x * 256 + threadIdx.x) * 4;
  float4 v = *(const float4*)(in + i);
  short4 o;
  o.x = f2bf(v.x); o.y = f2bf(v.y); o.z = f2bf(v.z); o.w = f2bf(v.w);
  *(short4*)(out + i) = o;
}

// ---------------- epilogue index helper ----------------
__device__ inline long long out_idx(int omode, int osec, int m, int n, int ldc,
                                    int zb) {
  if (omode == 0) return (long long)m * ldc + n;
  if (omode == 1)
    return (long long)(m >> 8) * 131072 + (long long)(n >> 6) * 16384 +
           (m & 255) * 64 + (n & 63);
  if (omode == 2)
    return (long long)(zb >> 3) * 131072 + (zb & 7) * 64 +
           (long long)m * 512 + n;
  const int sec = (n >> 9) + osec;
  const int d = n & 511;
  if (sec < 2)
    return (long long)sec * 1048576 +
           (((long long)(m >> 8) * 8 + (d >> 6)) * 256 + (m & 255)) * 64 +
           (d & 63);
  return 2LL * 1048576 + (long long)m * 512 + d;
}

// ---------------- 128x128 MFMA GEMM, VGPR-staged, coalesced ------------------
// A: M x K bf16 (lda), W: N x K bf16 (ldw). Stream-batched (z = stream).
// BK=32. Staging: per thread 2x16B per operand at rows (tid>>2) and
// (tid>>2)+64, kg=tid&3 -> 64B-coalesced global segments. LDS planes
// [kg][row][8] with kg stride 1040 shorts (pad 16) -> <=2-way on write & read.
// 4 waves = 2x2 quadrants of 64x64; per slab 8 ds_read_b128 -> 8 MFMAs/wave.
__global__ __launch_bounds__(256) void gemm128(
    const short* __restrict__ A, int lda, long long sAo,
    const short* __restrict__ W, int ldw, long long sWo,
    const float* __restrict__ bias, long long sBias,
    const float* __restrict__ res, long long sRes,
    float* __restrict__ C, short* __restrict__ Cbf, int ldc, long long sCo,
    int K, int act, int omode, int osec) {
  const int P = 1040;                        // kg plane stride (shorts)
  __shared__ short Asl[4 * 1040];
  __shared__ short Bsl[4 * 1040];
  const int zs = blockIdx.z;
  A += sAo * zs; W += sWo * zs;
  if (C) C += sCo * zs;
  if (Cbf) Cbf += sCo * zs;
  const int m0 = blockIdx.y * 128, n0 = blockIdx.x * 128;
  const int tid = threadIdx.x, lane = tid & 63, wv = tid >> 6;
  const int mq = (wv & 1) * 64, nq = (wv >> 1) * 64;
  const int r31 = lane & 31, half = lane >> 5;
  const int mA = tid >> 2, kgA = tid & 3;
  floatx16 acc[2][2] = {};
  const short* pa0 = A + (long long)(m0 + mA) * lda + kgA * 8;
  const short* pa1 = A + (long long)(m0 + mA + 64) * lda + kgA * 8;
  const short* pb0 = W + (long long)(n0 + mA) * ldw + kgA * 8;
  const short* pb1 = W + (long long)(n0 + mA + 64) * ldw + kgA * 8;
  short* wa0 = Asl + kgA * P + mA * 8;
  short* wa1 = wa0 + 64 * 8;
  short* wb0 = Bsl + kgA * P + mA * 8;
  short* wb1 = wb0 + 64 * 8;
  const short* raL = Asl + half * P + (mq + r31) * 8;
  const short* raH = Asl + (2 + half) * P + (mq + r31) * 8;
  const short* rbL = Bsl + half * P + (nq + r31) * 8;
  const short* rbH = Bsl + (2 + half) * P + (nq + r31) * 8;
  bf16x8 av0 = *(const bf16x8*)pa0;
  bf16x8 av1 = *(const bf16x8*)pa1;
  bf16x8 bv0 = *(const bf16x8*)pb0;
  bf16x8 bv1 = *(const bf16x8*)pb1;
  for (int k0 = 0; k0 < K; k0 += 32) {
    __syncthreads();   // previous slab's fragment reads done
    *(bf16x8*)wa0 = av0;
    *(bf16x8*)wa1 = av1;
    *(bf16x8*)wb0 = bv0;
    *(bf16x8*)wb1 = bv1;
    __syncthreads();
    if (k0 + 32 < K) {  // prefetch next slab, overlapped with MFMAs
      av0 = *(const bf16x8*)(pa0 + k0 + 32);
      av1 = *(const bf16x8*)(pa1 + k0 + 32);
      bv0 = *(const bf16x8*)(pb0 + k0 + 32);
      bv1 = *(const bf16x8*)(pb1 + k0 + 32);
    }
    const bf16x8 a0L = *(const bf16x8*)raL;
    const bf16x8 a0H = *(const bf16x8*)raH;
    const bf16x8 a1L = *(const bf16x8*)(raL + 32 * 8);
    const bf16x8 a1H = *(const bf16x8*)(raH + 32 * 8);
    const bf16x8 b0L = *(const bf16x8*)rbL;
    const bf16x8 b0H = *(const bf16x8*)rbH;
    const bf16x8 b1L = *(const bf16x8*)(rbL + 32 * 8);
    const bf16x8 b1H = *(const bf16x8*)(rbH + 32 * 8);
    acc[0][0] = __builtin_amdgcn_mfma_f32_32x32x16_bf16(a0L, b0L, acc[0][0], 0, 0, 0);
    acc[0][0] = __builtin_amdgcn_mfma_f32_32x32x16_bf16(a0H, b0H, acc[0][0], 0, 0, 0);
    acc[0][1] = __builtin_amdgcn_mfma_f32_32x32x16_bf16(a0L, b1L, acc[0][1], 0, 0, 0);
    acc[0][1] = __builtin_amdgcn_mfma_f32_32x32x16_bf16(a0H, b1H, acc[0][1], 0, 0, 0);
    acc[1][0] = __builtin_amdgcn_mfma_f32_32x32x16_bf16(a1L, b0L, acc[1][0], 0, 0, 0);
    acc[1][0] = __builtin_amdgcn_mfma_f32_32x32x16_bf16(a1H, b0H, acc[1][0], 0, 0, 0);
    acc[1][1] = __builtin_amdgcn_mfma_f32_32x32x16_bf16(a1L, b1L, acc[1][1], 0, 0, 0);
    acc[1][1] = __builtin_amdgcn_mfma_f32_32x32x16_bf16(a1H, b1H, acc[1][1], 0, 0, 0);
  }
#pragma unroll
  for (int j = 0; j < 2; ++j) {
    const int n = n0 + nq + j * 32 + r31;
    const float bvb = bias ? bias[sBias * zs + n] : 0.f;
#pragma unroll
    for (int i = 0; i < 2; ++i) {
#pragma unroll
      for (int r = 0; r < 16; ++r) {
        const int m = m0 + mq + i * 32 + (r & 3) + 8 * (r >> 2) + 4 * half;
        float v = acc[i][j][r] + bvb;
        if (act == 1) v = fmaxf(v, 0.f) + log1pf(expf(-fabsf(v)));
        else if (act == 2) v = fmaxf(v, 0.f);
        if (res) v += res[sRes * zs + (long long)m * ldc + n];
        const long long idx = out_idx(omode, osec, m, n, ldc, 0);
        if (C) C[idx] = v;
        if (Cbf) Cbf[idx] = f2bf(v);
      }
    }
  }
}

// ---------------- bf16 MFMA GEMM 64-tile, generalized batch ------------------
__global__ __launch_bounds__(256) void gemm_bf16(
    const short* __restrict__ A, int lda, long long sA, long long sAo,
    const short* __restrict__ W, int ldw, long long sW, long long sWo,
    const float* __restrict__ bias, long long sBias,
    const float* __restrict__ res, long long sRes,
    float* __restrict__ C, short* __restrict__ Cbf, int ldc,
    long long sC, long long sCo,
    int K, float alpha, int act, int omode, int osec, int zdiv) {
  __shared__ short As[4 * 528];
  __shared__ short Bs[4 * 528];
  const int bz = blockIdx.z;
  const int zs = bz / zdiv, zb = bz % zdiv;
  A += sA * zb + sAo * zs;
  W += sW * zb + sWo * zs;
  if (C) C += sC * zb + sCo * zs;
  if (Cbf) Cbf += sC * zb + sCo * zs;
  const int m0 = blockIdx.y * 64, n0 = blockIdx.x * 64;
  const int tid = threadIdx.x, lane = tid & 63, wv = tid >> 6;
  const int mq = (wv & 1) * 32, nq = (wv >> 1) * 32;
  const int r31 = lane & 31, half = lane >> 5;
  const int mA = tid >> 2, kgA = tid & 3;
  floatx16 acc = {};
  const short* pa = A + (long long)(m0 + mA) * lda + kgA * 8;
  const short* pb = W + (long long)(n0 + mA) * ldw + kgA * 8;
  short* wa = As + kgA * 528 + mA * 8;
  short* wb = Bs + kgA * 528 + mA * 8;
  const short* ra = As + (mq + r31) * 8 + half * 528;
  const short* rb = Bs + (nq + r31) * 8 + half * 528;
  bf16x8 av = *(const bf16x8*)pa;
  bf16x8 bv = *(const bf16x8*)pb;
  for (int k0 = 0; k0 < K; k0 += 32) {
    __syncthreads();
    *(bf16x8*)wa = av;
    *(bf16x8*)wb = bv;
    __syncthreads();
    if (k0 + 32 < K) {
      av = *(const bf16x8*)(pa + k0 + 32);
      bv = *(const bf16x8*)(pb + k0 + 32);
    }
    acc = __builtin_amdgcn_mfma_f32_32x32x16_bf16(
        *(const bf16x8*)ra, *(const bf16x8*)rb, acc, 0, 0, 0);
    acc = __builtin_amdgcn_mfma_f32_32x32x16_bf16(
        *(const bf16x8*)(ra + 2 * 528), *(const bf16x8*)(rb + 2 * 528), acc, 0, 0, 0);
  }
  const int n = n0 + nq + r31;
  const float bvb = bias ? bias[sBias * zs + n] : 0.f;
#pragma unroll
  for (int r = 0; r < 16; ++r) {
    const int m = m0 + mq + (r & 3) + 8 * (r >> 2) + 4 * half;
    float v = acc[r] * alpha + bvb;
    if (act == 1) v = fmaxf(v, 0.f) + log1pf(expf(-fabsf(v)));
    else if (act == 2) v = fmaxf(v, 0.f);
    if (res) v += res[sRes * zs + (long long)m * ldc + n];
    const long long idx = out_idx(omode, osec, m, n, ldc, zb);
    if (C) C[idx] = v;
    if (Cbf) Cbf[idx] = f2bf(v);
  }
}

// ---------------- LayerNorm, stream-batched (2048 rows/stream) ----------------
__device__ inline float pe_val(int bi, int c) {
  float f = expf((float)(c & ~1) * (-9.210340371976184f / 512.f));
  float arg = (float)bi * f;
  return (c & 1) ? cosf(arg) : sinf(arg);
}
__global__ __launch_bounds__(256) void ln_kernel(
    const float* __restrict__ in1, long long s1,
    const float* __restrict__ in2, long long s2,
    const float* __restrict__ in3,
    const float* __restrict__ g, const float* __restrict__ bb, long long sg,
    float* __restrict__ out, short* __restrict__ obf, long long so,
    int mode, int add_pe) {
  __shared__ float sm[4];
  const int row = blockIdx.x, tid = threadIdx.x;
  const int stream = row >> 11, lr = row & 2047;
  in1 += stream * s1;
  if (in2) in2 += stream * s2;
  g += stream * sg; bb += stream * sg;
  const long long base = (long long)lr * 512;
  const long long obase = stream * so + base;
  float x0 = in1[base + tid];
  float x1 = in1[base + tid + 256];
  if (in2) { x0 += in2[base + tid]; x1 += in2[base + tid + 256]; }
  if (in3) { x0 += in3[base + tid]; x1 += in3[base + tid + 256]; }
  if (add_pe) {
    int bi = lr >> 8;
    x0 += pe_val(bi, tid);
    x1 += pe_val(bi, tid + 256);
  }
  float m = block_sum(x0 + x1, sm) * (1.f / 512.f);
  float d0 = x0 - m, d1 = x1 - m;
  float ss = block_sum(d0 * d0 + d1 * d1, sm);
  float r0, r1;
  if (mode == 0) {
    float rstd = rsqrtf(ss * (1.f / 512.f) + 1e-5f);
    r0 = d0 * rstd * g[tid] + bb[tid];
    r1 = d1 * rstd * g[tid + 256] + bb[tid + 256];
  } else {
    float s = sqrtf(ss * (1.f / 511.f));
    float inv = 1.f / (s + 1e-6f);
    r0 = g[tid] * d0 * inv + bb[tid];
    r1 = g[tid + 256] * d1 * inv + bb[tid + 256];
  }
  if (out) { out[obase + tid] = r0; out[obase + tid + 256] = r1; }
  if (obf) { obf[obase + tid] = f2bf(r0); obf[obase + tid + 256] = f2bf(r1); }
}

// ---------------- causal depthwise conv + SiLU, 3-layer batched ----------------
__global__ __launch_bounds__(256) void conv_silu(
    const float* __restrict__ xz, const float* __restrict__ cw,
    const float* __restrict__ cb, float* __restrict__ u2,
    short* __restrict__ u2bf) {
  int gid = blockIdx.x * 256 + threadIdx.x;
  int lay = gid >> 21;
  int idx = gid & 2097151;
  int c = idx & 1023, t = (idx >> 10) & 255, b = idx >> 18;
  const float* base = xz + (long long)lay * 4194304 + (long long)b * 256 * 2048;
  cw += lay * 4096; cb += lay * 1024;
  float acc = cb[c];
#pragma unroll
  for (int k = 0; k < 4; ++k) {
    int tt = t + k - 3;
    if (tt >= 0) acc += base[tt * 2048 + c] * cw[c * 4 + k];
  }
  float v = acc / (1.f + expf(-acc));
  u2[gid] = v;
  u2bf[gid] = f2bf(v);
}

// ---------------- selective-scan: 4 s/lane, 64 d/block, T=32 chunks ----------
// Wave = 16 d x 4 si (si holds s = si*4..si*4+3). h[4] in registers;
// reduction = 3 in-reg FMAs + 2 shfls. grid (16, 24): lay=y>>3, b=y&7.
// LDS 36 KB -> 4 blocks/CU. Register prefetch of next chunk.
__global__ __launch_bounds__(256) void scan_kernel(
    const float* __restrict__ delta, const float* __restrict__ u2,
    const float* __restrict__ xz, const float* __restrict__ xdbl,
    const float* __restrict__ Alog, const float* __restrict__ Dp,
    short* __restrict__ ys) {
  __shared__ float sdel[32][64];
  __shared__ float su[32][64];
  __shared__ float sz[32][64];
  __shared__ float sxd[32][32];
  __shared__ float sy[32][64];
  const int lay = blockIdx.y >> 3, b = blockIdx.y & 7;
  delta += (long long)lay * 2097152;
  u2 += (long long)lay * 2097152;
  xz += (long long)lay * 4194304;
  xdbl += (long long)lay * 131072;
  Alog += lay * 16384;
  Dp += lay * 1024;
  ys += (long long)lay * 2097152;
  const int tid = threadIdx.x;
  const int lane = tid & 63;
  const int wv = tid >> 6;
  const int si = lane & 3;
  const int dl = wv * 16 + (lane >> 2);   // 0..63
  const int d0 = blockIdx.x * 64;
  const int d = d0 + dl;
  float A[4];
#pragma unroll
  for (int j = 0; j < 4; ++j) A[j] = -expf(Alog[d * 16 + si * 4 + j]);
  const float Dd = Dp[d];
  const long long rowbase = (long long)b * 256;
  float rdel[8], ru[8], rz[8], rxd[4];
  auto issue = [&](int c) {
    const int t0 = c * 32;
#pragma unroll
    for (int k = 0; k < 8; ++k) {
      int e = k * 256 + tid;
      int t = e >> 6, dd = e & 63;
      long long r = rowbase + t0 + t;
      rdel[k] = delta[r * 1024 + d0 + dd];
      ru[k]   = u2[r * 1024 + d0 + dd];
      rz[k]   = xz[r * 2048 + 1024 + d0 + dd];
    }
#pragma unroll
    for (int k = 0; k < 4; ++k) {
      int e = k * 256 + tid;
      int t = e >> 5, j = e & 31;
      rxd[k] = xdbl[(rowbase + t0 + t) * 64 + 32 + j];
    }
  };
  auto commit = [&]() {
#pragma unroll
    for (int k = 0; k < 8; ++k) {
      int e = k * 256 + tid;
      int t = e >> 6, dd = e & 63;
      sdel[t][dd] = rdel[k]; su[t][dd] = ru[k]; sz[t][dd] = rz[k];
    }
#pragma unroll
    for (int k = 0; k < 4; ++k) {
      int e = k * 256 + tid;
      int t = e >> 5, j = e & 31;
      sxd[t][j] = rxd[k];
    }
  };
  issue(0);
  commit();
  float h0 = 0.f, h1 = 0.f, h2 = 0.f, h3 = 0.f;
  for (int c = 0; c < 8; ++c) {
    __syncthreads();                 // buffer ready
    if (c < 7) issue(c + 1);         // next chunk loads overlap compute
#pragma unroll 4
    for (int t = 0; t < 32; ++t) {
      const float dt = sdel[t][dl];
      const float uu = su[t][dl];
      const float4 Bv = *(const float4*)&sxd[t][si * 4];
      const float4 Cv = *(const float4*)&sxd[t][16 + si * 4];
      const float du = dt * uu;
      h0 = __expf(dt * A[0]) * h0 + du * Bv.x;
      h1 = __expf(dt * A[1]) * h1 + du * Bv.y;
      h2 = __expf(dt * A[2]) * h2 + du * Bv.z;
      h3 = __expf(dt * A[3]) * h3 + du * Bv.w;
      float p = h0 * Cv.x + h1 * Cv.y + h2 * Cv.z + h3 * Cv.w;
      p += __shfl_xor(p, 1, 64);
      p += __shfl_xor(p, 2, 64);
      if (si == 0) {
        const float zz = sz[t][dl];
        sy[t][dl] = (p + Dd * uu) * (zz / (1.f + expf(-zz)));
      }
    }
    __syncthreads();                 // sy complete; buffer reads done
    const int t0 = c * 32;
#pragma unroll
    for (int k = 0; k < 8; ++k) {
      int e = k * 256 + tid;
      int t = e >> 6, dd = e & 63;
      ys[(rowbase + t0 + t) * 1024 + d0 + dd] = f2bf(sy[t][dd]);
    }
    if (c < 7) commit();
  }
}

// ---------------- softmax rows of 256: f32 in -> bf16 out ----------------
__global__ __launch_bounds__(256) void softmax_rows(const float* __restrict__ S,
                                                    short* __restrict__ Sbf) {
  __shared__ float sm[4];
  const float* p = S + (long long)blockIdx.x * 256;
  float v = p[threadIdx.x];
  float m = block_max(v, sm);
  float e = expf(v - m);
  float s = block_sum(e, sm);
  Sbf[(long long)blockIdx.x * 256 + threadIdx.x] = f2bf(e / s);
}

// ---------------- V transpose (bf16, 3 streams): -> (B,H,hd,S) ----------------
__global__ __launch_bounds__(256) void to_heads_t(const short* __restrict__ in,
                                                  short* __restrict__ out) {
  int e = blockIdx.x * 256 + threadIdx.x;
  int stream = e >> 20;
  int inner = e & 1048575;
  int s = inner & 255, c = (inner >> 8) & 63, h = (inner >> 14) & 7, b = inner >> 17;
  out[(long long)stream * 1048576 + inner] =
      in[(long long)stream * 3145728 + 2097152 + ((b * 256 + s) * 512) + h * 64 + c];
}

// ---------------- host orchestration ----------------
extern "C" void kernel_launch(void* const* d_in, const int* in_sizes, int n_in,
                              void* d_out, int out_size, void* d_ws, size_t ws_size,
                              hipStream_t stream) {
  (void)in_sizes; (void)n_in; (void)out_size; (void)ws_size;
  const float* text   = (const float*)d_in[0];
  const float* video  = (const float*)d_in[1];
  const float* audio  = (const float*)d_in[2];
  const float* emb_w  = (const float*)d_in[3];
  const float* emb_b  = (const float*)d_in[4];
  const float* ada_a  = (const float*)d_in[5];
  const float* ada_b  = (const float*)d_in[6];
  const float* m_in_w = (const float*)d_in[7];
  const float* m_cw   = (const float*)d_in[8];
  const float* m_cb   = (const float*)d_in[9];
  const float* m_xp   = (const float*)d_in[10];
  const float* m_dtw  = (const float*)d_in[11];
  const float* m_dtb  = (const float*)d_in[12];
  const float* m_Alog = (const float*)d_in[13];
  const float* m_Dp   = (const float*)d_in[14];
  const float* m_ow   = (const float*)d_in[15];
  const float* m_lng  = (const float*)d_in[16];
  const float* m_lnb  = (const float*)d_in[17];
  const float* qkv_w  = (const float*)d_in[18];
  const float* qkv_b  = (const float*)d_in[19];
  const float* aout_w = (const float*)d_in[20];
  const float* aout_b = (const float*)d_in[21];
  const float* sln_g  = (const float*)d_in[22];
  const float* sln_b  = (const float*)d_in[23];
  const float* f_w1   = (const float*)d_in[24];
  const float* f_b1   = (const float*)d_in[25];
  const float* f_w2   = (const float*)d_in[26];
  const float* f_b2   = (const float*)d_in[27];
  const float* f_lng  = (const float*)d_in[28];
  const float* f_lnb  = (const float*)d_in[29];
  const float* n1_g   = (const float*)d_in[30];
  const float* n1_b   = (const float*)d_in[31];
  float* outp = (float*)d_out;

  const long long MF = 1048576;   // 2048*512

  // ---------- workspace arenas ----------
  float* ws = (float*)d_ws;
  size_t off = 0;
  auto alloc = [&](size_t n) { float* p = ws + off; off += n; return p; };
  auto allocs = [&](size_t n_bf16) { return (short*)alloc((n_bf16 + 1) / 2); };
  float* sb0    = alloc(6 * MF);
  short* sbbf0  = allocs(6 * MF);
  short* inbf   = allocs(3 * MF);
  float* xzA    = alloc(3 * 4194304);       // xz | scoresF
  float* u2A    = alloc(3 * 2097152);       // u2 f32 | scoresBf
  float* dlA    = alloc(3 * 2097152);       // dl f32 | qkvA (9M shorts)
  short* ysA    = allocs(3 * 2097152);      // ys bf16 | vtA+obA
  float* xdblA  = alloc(3 * 131072);
  short* xdblbfA= allocs(3 * 131072);
  float* mtmpA  = alloc(3 * MF);            // mtmp | h2
  short* u2bfA  = allocs(3 * 2097152);      // u2bf | hbufbf
  short* n1bfA  = allocs(3 * MF);
  short* n2bfA  = allocs(3 * MF);
  short* embbf   = allocs(512 * 512);
  short* minbf   = allocs(6 * 1048576);
  short* mxpbf   = allocs(6 * 65536);
  short* mdtwbf  = allocs(6 * 32768);
  short* mowbf   = allocs(6 * 524288);
  short* qkvwbf  = allocs(9 * 786432);
  short* aoutwbf = allocs(9 * 262144);
  short* fw1bf   = allocs(3 * 524288);
  short* fw2bf   = allocs(3 * 524288);

  float* scoresF  = xzA;
  short* scoresBf = (short*)u2A;
  short* qkvA     = (short*)dlA;
  short* vtA      = ysA;
  short* obA      = ysA + 3145728;
  short* hbufbfA  = u2bfA;
  float* h2A      = mtmpA;

  auto cvt = [&](const float* in, short* out, int n) {
    cvt_bf16<<<n / 1024, 256, 0, stream>>>(in, out);
  };
  auto gemm = [&](const short* A, int lda, long long sA, long long sAo,
                  const short* W, int ldw, long long sW, long long sWo,
                  const float* bias, long long sB,
                  const float* res, long long sR,
                  float* C, short* Cbf, int ldc, long long sC, long long sCo,
                  int M, int N, int K, float alpha, int act,
                  int omode, int osec, int zdiv, int batch) {
    dim3 g(N / 64, M / 64, batch);
    gemm_bf16<<<g, 256, 0, stream>>>(A, lda, sA, sAo, W, ldw, sW, sWo,
                                     bias, sB, res, sR, C, Cbf, ldc, sC, sCo,
                                     K, alpha, act, omode, osec, zdiv);
  };
  auto g128 = [&](const short* A, int lda, long long sAo,
                  const short* W, int ldw, long long sWo,
                  const float* bias, long long sB,
                  const float* res, long long sR,
                  float* C, short* Cbf, int ldc, long long sCo,
                  int M, int N, int K, int act, int omode, int osec) {
    dim3 g(N / 128, M / 128, 3);
    gemm128<<<g, 256, 0, stream>>>(A, lda, sAo, W, ldw, sWo, bias, sB,
                                   res, sR, C, Cbf, ldc, sCo, K, act,
                                   omode, osec);
  };
  auto ln = [&](const float* i1, long long s1, const float* i2, long long s2,
                const float* i3, const float* g, const float* b, long long sg,
                float* o, short* obf, long long so, int mode, int pe,
                int nblocks) {
    ln_kernel<<<nblocks, 256, 0, stream>>>(i1, s1, i2, s2, i3, g, b, sg,
                                           o, obf, so, mode, pe);
  };

  // ---- pre-convert all weights to bf16 ----
  cvt(emb_w,  embbf,   512 * 512);
  cvt(m_in_w, minbf,   6 * 1048576);
  cvt(m_xp,   mxpbf,   6 * 65536);
  cvt(m_dtw,  mdtwbf,  6 * 32768);
  cvt(m_ow,   mowbf,   6 * 524288);
  cvt(qkv_w,  qkvwbf,  9 * 786432);
  cvt(aout_w, aoutwbf, 9 * 262144);
  cvt(f_w1,   fw1bf,   3 * 524288);
  cvt(f_w2,   fw2bf,   3 * 524288);

  // ---- mamba group (layers g0..g0+2 on sb[0..2]) ----
  auto mamba3 = [&](int g0) {
    g128(sbbf0, 512, MF,  minbf + (size_t)g0 * 1048576, 512, 1048576,
         nullptr, 0, nullptr, 0,  xzA, nullptr, 2048, 4194304,
         2048, 2048, 512, 0, 0, 0);
    conv_silu<<<24576, 256, 0, stream>>>(xzA, m_cw + (size_t)g0 * 4096,
                                         m_cb + (size_t)g0 * 1024, u2A, u2bfA);
    gemm(u2bfA, 1024, 0, 2097152,  mxpbf + (size_t)g0 * 65536, 1024, 0, 65536,
         nullptr, 0, nullptr, 0,  xdblA, xdblbfA, 64, 0, 131072,
         2048, 64, 1024, 1.f, 0, 0, 0, 1, 3);
    gemm(xdblbfA, 64, 0, 131072,  mdtwbf + (size_t)g0 * 32768, 32, 0, 32768,
         m_dtb + (size_t)g0 * 1024, 1024, nullptr, 0,
         dlA, nullptr, 1024, 0, 2097152,
         2048, 1024, 32, 1.f, 1, 0, 0, 1, 3);
    scan_kernel<<<dim3(16, 24), 256, 0, stream>>>(
        dlA, u2A, xzA, xdblA, m_Alog + (size_t)g0 * 16384,
        m_Dp + (size_t)g0 * 1024, ysA);
    g128(ysA, 1024, 2097152,  mowbf + (size_t)g0 * 524288, 1024, 524288,
         nullptr, 0, nullptr, 0,  mtmpA, nullptr, 512, MF,
         2048, 512, 1024, 0, 0, 0);
    ln(sb0, MF, mtmpA, MF, nullptr, m_lng + (size_t)g0 * 512,
       m_lnb + (size_t)g0 * 512, 512, sb0, sbbf0, MF, 0, 0, 6144);
  };

  // ---- attention core (after q/k/v in qkvA) ----
  auto attn_core = [&](int i0, const float* s1b, float* outb, short* outbfb) {
    to_heads_t<<<12288, 256, 0, stream>>>(qkvA, vtA);
    gemm(qkvA, 64, 16384, 3 * MF,  qkvA + MF, 64, 16384, 3 * MF,
         nullptr, 0, nullptr, 0,  scoresF, nullptr, 256, 65536, 4194304,
         256, 256, 64, 0.125f, 0, 0, 0, 64, 192);
    softmax_rows<<<49152, 256, 0, stream>>>(scoresF, scoresBf);
    gemm(scoresBf, 256, 65536, 4194304,  vtA, 256, 16384, MF,
         nullptr, 0, nullptr, 0,  nullptr, obA, 512, 0, MF,
         256, 64, 256, 1.f, 0, 2, 0, 64, 192);
    g128(obA, 512, MF,  aoutwbf + (size_t)i0 * 262144, 512, 262144,
         aout_b + (size_t)i0 * 512, 512,  s1b, MF,
         outb, outbfb, 512, MF, 2048, 512, 512, 0, 0, 0);
  };

  auto attn_self = [&](int i0, const float* s1b, float* outb, short* outbfb) {
    ln(s1b, MF, nullptr, 0, nullptr, sln_g + (size_t)i0 * 512,
       sln_b + (size_t)i0 * 512, 512, nullptr, n1bfA, MF, 0, 0, 6144);
    g128(n1bfA, 512, MF,  qkvwbf + (size_t)i0 * 786432, 512, 786432,
         qkv_b + (size_t)i0 * 1536, 1536, nullptr, 0,
         nullptr, qkvA, 0, 3 * MF, 2048, 1536, 512, 0, 3, 0);
    attn_core(i0, s1b, outb, outbfb);
  };

  auto attn_cross = [&](int i0, const float* s1b, const float* s2p0,
                        const float* s2p1, const float* s2p2,
                        float* outb, short* outbfb) {
    ln(s1b, MF, nullptr, 0, nullptr, sln_g + (size_t)i0 * 512,
       sln_b + (size_t)i0 * 512, 512, nullptr, n1bfA, MF, 0, 0, 6144);
    const float* s2p[3] = {s2p0, s2p1, s2p2};
    for (int s = 0; s < 3; ++s)
      ln(s2p[s], 0, nullptr, 0, nullptr, sln_g + (size_t)(i0 + s) * 512,
         sln_b + (size_t)(i0 + s) * 512, 0, nullptr, n2bfA + s * MF, 0,
         0, 0, 2048);
    g128(n1bfA, 512, MF,  qkvwbf + (size_t)i0 * 786432, 512, 786432,
         qkv_b + (size_t)i0 * 1536, 1536, nullptr, 0,
         nullptr, qkvA, 0, 3 * MF, 2048, 512, 512, 0, 1, 0);
    g128(n2bfA, 512, MF,  qkvwbf + (size_t)i0 * 786432 + 262144, 512, 786432,
         qkv_b + (size_t)i0 * 1536 + 512, 1536, nullptr, 0,
         nullptr, qkvA, 0, 3 * MF, 2048, 1024, 512, 0, 3, 1);
    attn_core(i0, s1b, outb, outbfb);
  };

  // ---- stems ----
  const float* ins[3] = {text, video, audio};
  for (int j = 0; j < 3; ++j) cvt(ins[j], inbf + j * MF, MF);
  g128(inbf, 512, MF,  embbf, 512, 0,  emb_b, 0, nullptr, 0,
       sb0, nullptr, 512, MF, 2048, 512, 512, 0, 0, 0);
  ln(sb0, MF, nullptr, 0, nullptr, ada_a, ada_b, 0, sb0, sbbf0, MF, 1, 1, 6144);
  // ---- mamba 0..2 ----
  mamba3(0);
  // ---- self attention 0..2: sb[0..2] -> sb[3..5] ----
  attn_self(0, sb0, sb0 + 3 * MF, nullptr);
  // ---- cross attention 3..5 ----
  attn_cross(3, sb0 + 3 * MF, sb0 + 5 * MF, sb0 + 3 * MF, sb0 + 4 * MF,
             sb0, sbbf0);
  // ---- mamba 3..5 ----
  mamba3(3);
  // ---- self attention 6..8: sb[0..2] -> sb[3..5] ----
  attn_self(6, sb0, sb0 + 3 * MF, sbbf0 + 3 * MF);
  // ---- ffn 0..2 on sb[3..5] ----
  g128(sbbf0 + 3 * MF, 512, MF,  fw1bf, 512, 524288,
       f_b1, 1024, nullptr, 0,  nullptr, hbufbfA, 1024, 2097152,
       2048, 1024, 512, 2, 0, 0);
  g128(hbufbfA, 1024, 2097152,  fw2bf, 1024, 524288,
       f_b2, 512, nullptr, 0,  h2A, nullptr, 512, MF,
       2048, 512, 1024, 0, 0, 0);
  ln(sb0 + 3 * MF, MF, h2A, MF, nullptr, f_lng, f_lnb, 512,
     sb0 + 3 * MF, nullptr, MF, 1, 0, 6144);
  // ---- final norm: torch_ln(t+v+a) -> out ----
  ln(sb0 + 3 * MF, 0, sb0 + 4 * MF, 0, sb0 + 5 * MF, n1_g, n1_b, 0,
     outp, nullptr, 0, 0, 0, 2048);
}

// Round 10
// 1136.571 us; speedup vs baseline: 1.6732x; 1.3804x over previous
//
#include <hip/hip_runtime.h>
#include <hip/hip_bf16.h>
#include <math.h>

// ---------------- constants ----------------
// B=8 S=256 D=512 H=8 hd=64 DI=1024 DS=16 DC=4 DTR=32 DF=1024
// rows = B*S = 2048, MF = 2048*512 = 1048576 elements per stream plane

using bf16x8 = __attribute__((ext_vector_type(8))) short;
using floatx16 = __attribute__((ext_vector_type(16))) float;

__device__ inline short f2bf(float x) {
  __hip_bfloat16 h = __float2bfloat16(x);
  return *reinterpret_cast<short*>(&h);
}
__device__ inline float bf2f(short s) {
  unsigned u = ((unsigned)(unsigned short)s) << 16;
  return __uint_as_float(u);
}

// ---------------- reduction helpers (blockDim == 256) ----------------
__device__ inline float wave_sum(float v) {
#pragma unroll
  for (int o = 32; o > 0; o >>= 1) v += __shfl_xor(v, o, 64);
  return v;
}
__device__ inline float wave_maxf(float v) {
#pragma unroll
  for (int o = 32; o > 0; o >>= 1) v = fmaxf(v, __shfl_xor(v, o, 64));
  return v;
}
__device__ inline float block_sum(float v, float* sm) {
  v = wave_sum(v);
  if ((threadIdx.x & 63) == 0) sm[threadIdx.x >> 6] = v;
  __syncthreads();
  float r = sm[0] + sm[1] + sm[2] + sm[3];
  __syncthreads();
  return r;
}
__device__ inline float block_max(float v, float* sm) {
  v = wave_maxf(v);
  if ((threadIdx.x & 63) == 0) sm[threadIdx.x >> 6] = v;
  __syncthreads();
  float r = fmaxf(fmaxf(sm[0], sm[1]), fmaxf(sm[2], sm[3]));
  __syncthreads();
  return r;
}

// ---------------- multi-segment f32 -> bf16 convert (one launch) -------------
struct CvtArgs {
  const float* src[12];
  short* dst[12];
  int blk_end[12];   // exclusive prefix of n/1024
  int nseg;
};
__global__ __launch_bounds__(256) void cvt_multi(CvtArgs a) {
  int b = blockIdx.x;
  int s = 0;
  while (b >= a.blk_end[s]) ++s;
  int b0 = s ? a.blk_end[s - 1] : 0;
  int i = ((b - b0) * 256 + threadIdx.x) * 4;
  float4 v = *(const float4*)(a.src[s] + i);
  short4 o;
  o.x = f2bf(v.x); o.y = f2bf(v.y); o.z = f2bf(v.z); o.w = f2bf(v.w);
  *(short4*)(a.dst[s] + i) = o;
}

// ---------------- epilogue index helper ----------------
__device__ inline long long out_idx(int omode, int osec, int m, int n, int ldc,
                                    int zb) {
  if (omode == 0) return (long long)m * ldc + n;
  if (omode == 1)
    return (long long)(m >> 8) * 131072 + (long long)(n >> 6) * 16384 +
           (m & 255) * 64 + (n & 63);
  if (omode == 2)
    return (long long)(zb >> 3) * 131072 + (zb & 7) * 64 +
           (long long)m * 512 + n;
  const int sec = (n >> 9) + osec;
  const int d = n & 511;
  if (sec < 2)
    return (long long)sec * 1048576 +
           (((long long)(m >> 8) * 8 + (d >> 6)) * 256 + (m & 255)) * 64 +
           (d & 63);
  return 2LL * 1048576 + (long long)m * 512 + d;
}

// ---------------- bf16 MFMA GEMM 64-tile, generalized batch ------------------
// z decodes as zs = z/zdiv (stream), zb = z%zdiv (inner, e.g. b*8+h).
__global__ __launch_bounds__(256) void gemm_bf16(
    const short* __restrict__ A, int lda, long long sA, long long sAo,
    const short* __restrict__ W, int ldw, long long sW, long long sWo,
    const float* __restrict__ bias, long long sBias,
    const float* __restrict__ res, long long sRes,
    float* __restrict__ C, short* __restrict__ Cbf, int ldc,
    long long sC, long long sCo,
    int K, float alpha, int act, int omode, int osec, int zdiv) {
  __shared__ short As[4 * 528];
  __shared__ short Bs[4 * 528];
  const int bz = blockIdx.z;
  const int zs = bz / zdiv, zb = bz % zdiv;
  A += sA * zb + sAo * zs;
  W += sW * zb + sWo * zs;
  if (C) C += sC * zb + sCo * zs;
  if (Cbf) Cbf += sC * zb + sCo * zs;
  const int m0 = blockIdx.y * 64, n0 = blockIdx.x * 64;
  const int tid = threadIdx.x, lane = tid & 63, wv = tid >> 6;
  const int mq = (wv & 1) * 32, nq = (wv >> 1) * 32;
  const int r31 = lane & 31, half = lane >> 5;
  const int mA = tid >> 2, kgA = tid & 3;
  floatx16 acc = {};
  const short* pa = A + (long long)(m0 + mA) * lda + kgA * 8;
  const short* pb = W + (long long)(n0 + mA) * ldw + kgA * 8;
  short* wa = As + kgA * 528 + mA * 8;
  short* wb = Bs + kgA * 528 + mA * 8;
  const short* ra = As + (mq + r31) * 8 + half * 528;
  const short* rb = Bs + (nq + r31) * 8 + half * 528;
  bf16x8 av = *(const bf16x8*)pa;
  bf16x8 bv = *(const bf16x8*)pb;
  for (int k0 = 0; k0 < K; k0 += 32) {
    __syncthreads();
    *(bf16x8*)wa = av;
    *(bf16x8*)wb = bv;
    __syncthreads();
    if (k0 + 32 < K) {
      av = *(const bf16x8*)(pa + k0 + 32);
      bv = *(const bf16x8*)(pb + k0 + 32);
    }
    acc = __builtin_amdgcn_mfma_f32_32x32x16_bf16(
        *(const bf16x8*)ra, *(const bf16x8*)rb, acc, 0, 0, 0);
    acc = __builtin_amdgcn_mfma_f32_32x32x16_bf16(
        *(const bf16x8*)(ra + 2 * 528), *(const bf16x8*)(rb + 2 * 528), acc, 0, 0, 0);
  }
  const int n = n0 + nq + r31;
  const float bvb = bias ? bias[sBias * zs + n] : 0.f;
#pragma unroll
  for (int r = 0; r < 16; ++r) {
    const int m = m0 + mq + (r & 3) + 8 * (r >> 2) + 4 * half;
    float v = acc[r] * alpha + bvb;
    if (act == 1) v = fmaxf(v, 0.f) + log1pf(expf(-fabsf(v)));
    else if (act == 2) v = fmaxf(v, 0.f);
    if (res) v += res[sRes * zs + (long long)m * ldc + n];
    const long long idx = out_idx(omode, osec, m, n, ldc, zb);
    if (C) C[idx] = v;
    if (Cbf) Cbf[idx] = f2bf(v);
  }
}

// ---------------- LayerNorm, stream-batched (2048 rows/stream) ----------------
__device__ inline float pe_val(int bi, int c) {
  float f = expf((float)(c & ~1) * (-9.210340371976184f / 512.f));
  float arg = (float)bi * f;
  return (c & 1) ? cosf(arg) : sinf(arg);
}
__global__ __launch_bounds__(256) void ln_kernel(
    const float* __restrict__ in1, long long s1,
    const float* __restrict__ in2, long long s2,
    const float* __restrict__ in3,
    const float* __restrict__ g, const float* __restrict__ bb, long long sg,
    float* __restrict__ out, short* __restrict__ obf, long long so,
    int mode, int add_pe) {
  __shared__ float sm[4];
  const int row = blockIdx.x, tid = threadIdx.x;
  const int stream = row >> 11, lr = row & 2047;
  in1 += stream * s1;
  if (in2) in2 += stream * s2;
  g += stream * sg; bb += stream * sg;
  const long long base = (long long)lr * 512;
  const long long obase = stream * so + base;
  float x0 = in1[base + tid];
  float x1 = in1[base + tid + 256];
  if (in2) { x0 += in2[base + tid]; x1 += in2[base + tid + 256]; }
  if (in3) { x0 += in3[base + tid]; x1 += in3[base + tid + 256]; }
  if (add_pe) {
    int bi = lr >> 8;
    x0 += pe_val(bi, tid);
    x1 += pe_val(bi, tid + 256);
  }
  float m = block_sum(x0 + x1, sm) * (1.f / 512.f);
  float d0 = x0 - m, d1 = x1 - m;
  float ss = block_sum(d0 * d0 + d1 * d1, sm);
  float r0, r1;
  if (mode == 0) {
    float rstd = rsqrtf(ss * (1.f / 512.f) + 1e-5f);
    r0 = d0 * rstd * g[tid] + bb[tid];
    r1 = d1 * rstd * g[tid + 256] + bb[tid + 256];
  } else {
    float s = sqrtf(ss * (1.f / 511.f));
    float inv = 1.f / (s + 1e-6f);
    r0 = g[tid] * d0 * inv + bb[tid];
    r1 = g[tid + 256] * d1 * inv + bb[tid + 256];
  }
  if (out) { out[obase + tid] = r0; out[obase + tid + 256] = r1; }
  if (obf) { obf[obase + tid] = f2bf(r0); obf[obase + tid + 256] = f2bf(r1); }
}

// ---------------- causal depthwise conv + SiLU, 3-layer batched ----------------
__global__ __launch_bounds__(256) void conv_silu(
    const float* __restrict__ xz, const float* __restrict__ cw,
    const float* __restrict__ cb, float* __restrict__ u2,
    short* __restrict__ u2bf) {
  int gid = blockIdx.x * 256 + threadIdx.x;
  int lay = gid >> 21;
  int idx = gid & 2097151;
  int c = idx & 1023, t = (idx >> 10) & 255, b = idx >> 18;
  const float* base = xz + (long long)lay * 4194304 + (long long)b * 256 * 2048;
  cw += lay * 4096; cb += lay * 1024;
  float acc = cb[c];
#pragma unroll
  for (int k = 0; k < 4; ++k) {
    int tt = t + k - 3;
    if (tt >= 0) acc += base[tt * 2048 + c] * cw[c * 4 + k];
  }
  float v = acc / (1.f + expf(-acc));
  u2[gid] = v;
  u2bf[gid] = f2bf(v);
}

// ---------------- selective-scan: 4 s/lane, 64 d/block, T=32 chunks ----------
__global__ __launch_bounds__(256) void scan_kernel(
    const float* __restrict__ delta, const float* __restrict__ u2,
    const float* __restrict__ xz, const float* __restrict__ xdbl,
    const float* __restrict__ Alog, const float* __restrict__ Dp,
    short* __restrict__ ys) {
  __shared__ float sdel[32][64];
  __shared__ float su[32][64];
  __shared__ float sz[32][64];
  __shared__ float sxd[32][32];
  __shared__ float sy[32][64];
  const int lay = blockIdx.y >> 3, b = blockIdx.y & 7;
  delta += (long long)lay * 2097152;
  u2 += (long long)lay * 2097152;
  xz += (long long)lay * 4194304;
  xdbl += (long long)lay * 131072;
  Alog += lay * 16384;
  Dp += lay * 1024;
  ys += (long long)lay * 2097152;
  const int tid = threadIdx.x;
  const int lane = tid & 63;
  const int wv = tid >> 6;
  const int si = lane & 3;
  const int dl = wv * 16 + (lane >> 2);   // 0..63
  const int d0 = blockIdx.x * 64;
  const int d = d0 + dl;
  float A[4];
#pragma unroll
  for (int j = 0; j < 4; ++j) A[j] = -expf(Alog[d * 16 + si * 4 + j]);
  const float Dd = Dp[d];
  const long long rowbase = (long long)b * 256;
  float rdel[8], ru[8], rz[8], rxd[4];
  auto issue = [&](int c) {
    const int t0 = c * 32;
#pragma unroll
    for (int k = 0; k < 8; ++k) {
      int e = k * 256 + tid;
      int t = e >> 6, dd = e & 63;
      long long r = rowbase + t0 + t;
      rdel[k] = delta[r * 1024 + d0 + dd];
      ru[k]   = u2[r * 1024 + d0 + dd];
      rz[k]   = xz[r * 2048 + 1024 + d0 + dd];
    }
#pragma unroll
    for (int k = 0; k < 4; ++k) {
      int e = k * 256 + tid;
      int t = e >> 5, j = e & 31;
      rxd[k] = xdbl[(rowbase + t0 + t) * 64 + 32 + j];
    }
  };
  auto commit = [&]() {
#pragma unroll
    for (int k = 0; k < 8; ++k) {
      int e = k * 256 + tid;
      int t = e >> 6, dd = e & 63;
      sdel[t][dd] = rdel[k]; su[t][dd] = ru[k]; sz[t][dd] = rz[k];
    }
#pragma unroll
    for (int k = 0; k < 4; ++k) {
      int e = k * 256 + tid;
      int t = e >> 5, j = e & 31;
      sxd[t][j] = rxd[k];
    }
  };
  issue(0);
  commit();
  float h0 = 0.f, h1 = 0.f, h2 = 0.f, h3 = 0.f;
  for (int c = 0; c < 8; ++c) {
    __syncthreads();
    if (c < 7) issue(c + 1);
#pragma unroll 4
    for (int t = 0; t < 32; ++t) {
      const float dt = sdel[t][dl];
      const float uu = su[t][dl];
      const float4 Bv = *(const float4*)&sxd[t][si * 4];
      const float4 Cv = *(const float4*)&sxd[t][16 + si * 4];
      const float du = dt * uu;
      h0 = __expf(dt * A[0]) * h0 + du * Bv.x;
      h1 = __expf(dt * A[1]) * h1 + du * Bv.y;
      h2 = __expf(dt * A[2]) * h2 + du * Bv.z;
      h3 = __expf(dt * A[3]) * h3 + du * Bv.w;
      float p = h0 * Cv.x + h1 * Cv.y + h2 * Cv.z + h3 * Cv.w;
      p += __shfl_xor(p, 1, 64);
      p += __shfl_xor(p, 2, 64);
      if (si == 0) {
        const float zz = sz[t][dl];
        sy[t][dl] = (p + Dd * uu) * (zz / (1.f + expf(-zz)));
      }
    }
    __syncthreads();
    const int t0 = c * 32;
#pragma unroll
    for (int k = 0; k < 8; ++k) {
      int e = k * 256 + tid;
      int t = e >> 6, dd = e & 63;
      ys[(rowbase + t0 + t) * 1024 + d0 + dd] = f2bf(sy[t][dd]);
    }
    if (c < 7) commit();
  }
}

// ---------------- softmax rows of 256: bf16 in -> bf16 out (in place) --------
__global__ __launch_bounds__(256) void softmax_rows(short* __restrict__ S) {
  __shared__ float sm[4];
  short* p = S + (long long)blockIdx.x * 256;
  float v = bf2f(p[threadIdx.x]);
  float m = block_max(v, sm);
  float e = expf(v - m);
  float s = block_sum(e, sm);
  p[threadIdx.x] = f2bf(e / s);
}

// ---------------- V transpose (bf16, 3 streams): -> (B,H,hd,S) ----------------
__global__ __launch_bounds__(256) void to_heads_t(const short* __restrict__ in,
                                                  short* __restrict__ out) {
  int e = blockIdx.x * 256 + threadIdx.x;
  int stream = e >> 20;
  int inner = e & 1048575;
  int s = inner & 255, c = (inner >> 8) & 63, h = (inner >> 14) & 7, b = inner >> 17;
  out[(long long)stream * 1048576 + inner] =
      in[(long long)stream * 3145728 + 2097152 + ((b * 256 + s) * 512) + h * 64 + c];
}

// ---------------- host orchestration ----------------
extern "C" void kernel_launch(void* const* d_in, const int* in_sizes, int n_in,
                              void* d_out, int out_size, void* d_ws, size_t ws_size,
                              hipStream_t stream) {
  (void)in_sizes; (void)n_in; (void)out_size; (void)ws_size;
  const float* text   = (const float*)d_in[0];
  const float* video  = (const float*)d_in[1];
  const float* audio  = (const float*)d_in[2];
  const float* emb_w  = (const float*)d_in[3];
  const float* emb_b  = (const float*)d_in[4];
  const float* ada_a  = (const float*)d_in[5];
  const float* ada_b  = (const float*)d_in[6];
  const float* m_in_w = (const float*)d_in[7];
  const float* m_cw   = (const float*)d_in[8];
  const float* m_cb   = (const float*)d_in[9];
  const float* m_xp   = (const float*)d_in[10];
  const float* m_dtw  = (const float*)d_in[11];
  const float* m_dtb  = (const float*)d_in[12];
  const float* m_Alog = (const float*)d_in[13];
  const float* m_Dp   = (const float*)d_in[14];
  const float* m_ow   = (const float*)d_in[15];
  const float* m_lng  = (const float*)d_in[16];
  const float* m_lnb  = (const float*)d_in[17];
  const float* qkv_w  = (const float*)d_in[18];
  const float* qkv_b  = (const float*)d_in[19];
  const float* aout_w = (const float*)d_in[20];
  const float* aout_b = (const float*)d_in[21];
  const float* sln_g  = (const float*)d_in[22];
  const float* sln_b  = (const float*)d_in[23];
  const float* f_w1   = (const float*)d_in[24];
  const float* f_b1   = (const float*)d_in[25];
  const float* f_w2   = (const float*)d_in[26];
  const float* f_b2   = (const float*)d_in[27];
  const float* f_lng  = (const float*)d_in[28];
  const float* f_lnb  = (const float*)d_in[29];
  const float* n1_g   = (const float*)d_in[30];
  const float* n1_b   = (const float*)d_in[31];
  float* outp = (float*)d_out;

  const long long MF = 1048576;   // 2048*512

  // ---------- workspace arenas ----------
  float* ws = (float*)d_ws;
  size_t off = 0;
  auto alloc = [&](size_t n) { float* p = ws + off; off += n; return p; };
  auto allocs = [&](size_t n_bf16) { return (short*)alloc((n_bf16 + 1) / 2); };
  float* sb0    = alloc(6 * MF);
  short* sbbf0  = allocs(6 * MF);
  short* inbf   = allocs(3 * MF);
  float* xzA    = alloc(3 * 4194304);       // xz f32
  float* u2A    = alloc(3 * 2097152);       // u2 f32 | scoresBf (bf16)
  float* dlA    = alloc(3 * 2097152);       // dl f32 | qkvA (9M shorts)
  short* ysA    = allocs(3 * 2097152);      // ys bf16 | vtA+obA
  float* xdblA  = alloc(3 * 131072);
  short* xdblbfA= allocs(3 * 131072);
  float* mtmpA  = alloc(3 * MF);            // mtmp | h2
  short* u2bfA  = allocs(3 * 2097152);      // u2bf | hbufbf
  short* n1bfA  = allocs(3 * MF);
  short* n2bfA  = allocs(3 * MF);
  short* embbf   = allocs(512 * 512);
  short* minbf   = allocs(6 * 1048576);
  short* mxpbf   = allocs(6 * 65536);
  short* mdtwbf  = allocs(6 * 32768);
  short* mowbf   = allocs(6 * 524288);
  short* qkvwbf  = allocs(9 * 786432);
  short* aoutwbf = allocs(9 * 262144);
  short* fw1bf   = allocs(3 * 524288);
  short* fw2bf   = allocs(3 * 524288);

  short* scoresBf = (short*)u2A;            // 3 x 4194304 shorts
  short* qkvA     = (short*)dlA;
  short* vtA      = ysA;
  short* obA      = ysA + 3145728;
  short* hbufbfA  = u2bfA;
  float* h2A      = mtmpA;

  auto gemm = [&](const short* A, int lda, long long sA, long long sAo,
                  const short* W, int ldw, long long sW, long long sWo,
                  const float* bias, long long sB,
                  const float* res, long long sR,
                  float* C, short* Cbf, int ldc, long long sC, long long sCo,
                  int M, int N, int K, float alpha, int act,
                  int omode, int osec, int zdiv, int batch) {
    dim3 g(N / 64, M / 64, batch);
    gemm_bf16<<<g, 256, 0, stream>>>(A, lda, sA, sAo, W, ldw, sW, sWo,
                                     bias, sB, res, sR, C, Cbf, ldc, sC, sCo,
                                     K, alpha, act, omode, osec, zdiv);
  };
  auto ln = [&](const float* i1, long long s1, const float* i2, long long s2,
                const float* i3, const float* g, const float* b, long long sg,
                float* o, short* obf, long long so, int mode, int pe,
                int nblocks) {
    ln_kernel<<<nblocks, 256, 0, stream>>>(i1, s1, i2, s2, i3, g, b, sg,
                                           o, obf, so, mode, pe);
  };

  // ---- pre-convert all weights + inputs to bf16: ONE launch ----
  {
    CvtArgs ca;
    const float* srcs[12] = {emb_w, m_in_w, m_xp, m_dtw, m_ow, qkv_w, aout_w,
                             f_w1, f_w2, text, video, audio};
    short* dsts[12] = {embbf, minbf, mxpbf, mdtwbf, mowbf, qkvwbf, aoutwbf,
                       fw1bf, fw2bf, inbf, inbf + MF, inbf + 2 * MF};
    int ns[12] = {512 * 512, 6 * 1048576, 6 * 65536, 6 * 32768, 6 * 524288,
                  9 * 786432, 9 * 262144, 3 * 524288, 3 * 524288,
                  (int)MF, (int)MF, (int)MF};
    int acc = 0;
    for (int i = 0; i < 12; ++i) {
      ca.src[i] = srcs[i]; ca.dst[i] = dsts[i];
      acc += ns[i] / 1024; ca.blk_end[i] = acc;
    }
    ca.nseg = 12;
    cvt_multi<<<acc, 256, 0, stream>>>(ca);
  }

  // ---- mamba group (layers g0..g0+2 on sb[0..2]) ----
  auto mamba3 = [&](int g0) {
    gemm(sbbf0, 512, 0, MF,  minbf + (size_t)g0 * 1048576, 512, 0, 1048576,
         nullptr, 0, nullptr, 0,  xzA, nullptr, 2048, 0, 4194304,
         2048, 2048, 512, 1.f, 0, 0, 0, 1, 3);
    conv_silu<<<24576, 256, 0, stream>>>(xzA, m_cw + (size_t)g0 * 4096,
                                         m_cb + (size_t)g0 * 1024, u2A, u2bfA);
    gemm(u2bfA, 1024, 0, 2097152,  mxpbf + (size_t)g0 * 65536, 1024, 0, 65536,
         nullptr, 0, nullptr, 0,  xdblA, xdblbfA, 64, 0, 131072,
         2048, 64, 1024, 1.f, 0, 0, 0, 1, 3);
    gemm(xdblbfA, 64, 0, 131072,  mdtwbf + (size_t)g0 * 32768, 32, 0, 32768,
         m_dtb + (size_t)g0 * 1024, 1024, nullptr, 0,
         dlA, nullptr, 1024, 0, 2097152,
         2048, 1024, 32, 1.f, 1, 0, 0, 1, 3);
    scan_kernel<<<dim3(16, 24), 256, 0, stream>>>(
        dlA, u2A, xzA, xdblA, m_Alog + (size_t)g0 * 16384,
        m_Dp + (size_t)g0 * 1024, ysA);
    gemm(ysA, 1024, 0, 2097152,  mowbf + (size_t)g0 * 524288, 1024, 0, 524288,
         nullptr, 0, nullptr, 0,  mtmpA, nullptr, 512, 0, MF,
         2048, 512, 1024, 1.f, 0, 0, 0, 1, 3);
    ln(sb0, MF, mtmpA, MF, nullptr, m_lng + (size_t)g0 * 512,
       m_lnb + (size_t)g0 * 512, 512, sb0, sbbf0, MF, 0, 0, 6144);
  };

  // ---- attention core (after q/k/v in qkvA) ----
  auto attn_core = [&](int i0, const float* s1b, float* outb, short* outbfb) {
    to_heads_t<<<12288, 256, 0, stream>>>(qkvA, vtA);
    // scores (bf16 direct) = (1/8) Qh @ Kh^T, batch 192 = stream x (b*8+h)
    gemm(qkvA, 64, 16384, 3 * MF,  qkvA + MF, 64, 16384, 3 * MF,
         nullptr, 0, nullptr, 0,  nullptr, scoresBf, 256, 65536, 4194304,
         256, 256, 64, 0.125f, 0, 0, 0, 64, 192);
    softmax_rows<<<49152, 256, 0, stream>>>(scoresBf);
    gemm(scoresBf, 256, 65536, 4194304,  vtA, 256, 16384, MF,
         nullptr, 0, nullptr, 0,  nullptr, obA, 512, 0, MF,
         256, 64, 256, 1.f, 0, 2, 0, 64, 192);
    gemm(obA, 512, 0, MF,  aoutwbf + (size_t)i0 * 262144, 512, 0, 262144,
         aout_b + (size_t)i0 * 512, 512,  s1b, MF,
         outb, outbfb, 512, 0, MF,
         2048, 512, 512, 1.f, 0, 0, 0, 1, 3);
  };

  auto attn_self = [&](int i0, const float* s1b, float* outb, short* outbfb) {
    ln(s1b, MF, nullptr, 0, nullptr, sln_g + (size_t)i0 * 512,
       sln_b + (size_t)i0 * 512, 512, nullptr, n1bfA, MF, 0, 0, 6144);
    gemm(n1bfA, 512, 0, MF,  qkvwbf + (size_t)i0 * 786432, 512, 0, 786432,
         qkv_b + (size_t)i0 * 1536, 1536, nullptr, 0,
         nullptr, qkvA, 0, 0, 3 * MF,
         2048, 1536, 512, 1.f, 0, 3, 0, 1, 3);
    attn_core(i0, s1b, outb, outbfb);
  };

  auto attn_cross = [&](int i0, const float* s1b, const float* s2p0,
                        const float* s2p1, const float* s2p2,
                        float* outb, short* outbfb) {
    ln(s1b, MF, nullptr, 0, nullptr, sln_g + (size_t)i0 * 512,
       sln_b + (size_t)i0 * 512, 512, nullptr, n1bfA, MF, 0, 0, 6144);
    const float* s2p[3] = {s2p0, s2p1, s2p2};
    for (int s = 0; s < 3; ++s)
      ln(s2p[s], 0, nullptr, 0, nullptr, sln_g + (size_t)(i0 + s) * 512,
         sln_b + (size_t)(i0 + s) * 512, 0, nullptr, n2bfA + s * MF, 0,
         0, 0, 2048);
    gemm(n1bfA, 512, 0, MF,  qkvwbf + (size_t)i0 * 786432, 512, 0, 786432,
         qkv_b + (size_t)i0 * 1536, 1536, nullptr, 0,
         nullptr, qkvA, 0, 0, 3 * MF,
         2048, 512, 512, 1.f, 0, 1, 0, 1, 3);
    gemm(n2bfA, 512, 0, MF,  qkvwbf + (size_t)i0 * 786432 + 262144, 512, 0, 786432,
         qkv_b + (size_t)i0 * 1536 + 512, 1536, nullptr, 0,
         nullptr, qkvA, 0, 0, 3 * MF,
         2048, 1024, 512, 1.f, 0, 3, 1, 1, 3);
    attn_core(i0, s1b, outb, outbfb);
  };

  // ---- stems ----
  gemm(inbf, 512, 0, MF,  embbf, 512, 0, 0,  emb_b, 0, nullptr, 0,
       sb0, nullptr, 512, 0, MF, 2048, 512, 512, 1.f, 0, 0, 0, 1, 3);
  ln(sb0, MF, nullptr, 0, nullptr, ada_a, ada_b, 0, sb0, sbbf0, MF, 1, 1, 6144);
  // ---- mamba 0..2 ----
  mamba3(0);
  // ---- self attention 0..2: sb[0..2] -> sb[3..5] ----
  attn_self(0, sb0, sb0 + 3 * MF, nullptr);
  // ---- cross attention 3..5 ----
  attn_cross(3, sb0 + 3 * MF, sb0 + 5 * MF, sb0 + 3 * MF, sb0 + 4 * MF,
             sb0, sbbf0);
  // ---- mamba 3..5 ----
  mamba3(3);
  // ---- self attention 6..8: sb[0..2] -> sb[3..5] ----
  attn_self(6, sb0, sb0 + 3 * MF, sbbf0 + 3 * MF);
  // ---- ffn 0..2 on sb[3..5] ----
  gemm(sbbf0 + 3 * MF, 512, 0, MF,  fw1bf, 512, 0, 524288,
       f_b1, 1024, nullptr, 0,  nullptr, hbufbfA, 1024, 0, 2097152,
       2048, 1024, 512, 1.f, 2, 0, 0, 1, 3);
  gemm(hbufbfA, 1024, 0, 2097152,  fw2bf, 1024, 0, 524288,
       f_b2, 512, nullptr, 0,  h2A, nullptr, 512, 0, MF,
       2048, 512, 1024, 1.f, 0, 0, 0, 1, 3);
  ln(sb0 + 3 * MF, MF, h2A, MF, nullptr, f_lng, f_lnb, 512,
     sb0 + 3 * MF, nullptr, MF, 1, 0, 6144);
  // ---- final norm: torch_ln(t+v+a) -> out ----
  ln(sb0 + 3 * MF, 0, sb0 + 4 * MF, 0, sb0 + 5 * MF, n1_g, n1_b, 0,
     outp, nullptr, 0, 0, 0, 2048);
}